// Round 1
// baseline (705.742 us; speedup 1.0000x reference)
//
#include <hip/hip_runtime.h>
#include <stdint.h>

#define B_ 2
#define S_ 2048
#define DIM_ 2048
#define H_ 16
#define KVH_ 4
#define HD_ 128

typedef short short8 __attribute__((ext_vector_type(8)));
typedef float f4 __attribute__((ext_vector_type(4)));
typedef unsigned short u16;

__device__ __forceinline__ float bf2f(u16 u) {
    unsigned int x = ((unsigned int)u) << 16;
    union { unsigned int i; float f; } c; c.i = x; return c.f;
}
__device__ __forceinline__ u16 f2bf(float f) {
    union { float f; unsigned int i; } c; c.f = f;
    unsigned int x = c.i;
    unsigned int r = (x + 0x7fffu + ((x >> 16) & 1u)) >> 16;
    return (u16)r;
}

// ---------------- fp32 -> bf16 cast (vectorized) ----------------
__global__ void cast4_kernel(const float* __restrict__ in, u16* __restrict__ out, int n4) {
    int i = blockIdx.x * blockDim.x + threadIdx.x;
    if (i < n4) {
        float4 v = ((const float4*)in)[i];
        ushort4 o;
        o.x = f2bf(v.x); o.y = f2bf(v.y); o.z = f2bf(v.z); o.w = f2bf(v.w);
        ((ushort4*)out)[i] = o;
    }
}

// ---------------- GEMM: C[M,N] = A[M,K] @ W[N,K]^T (bf16 in, fp32 acc) ----------------
// 64x64 tile per block, 256 threads = 4 waves, each wave 16 rows x 64 cols.
template<bool OUT_BF16>
__global__ __launch_bounds__(256) void gemm_bt(const u16* __restrict__ A,
                                               const u16* __restrict__ W,
                                               void* __restrict__ Cout,
                                               int M, int N, int K) {
    __shared__ u16 As[64 * 40];  // pad 32->40 elems: 2-way bank conflicts only
    __shared__ u16 Bs[64 * 40];
    int t = threadIdx.x;
    int m0 = blockIdx.y * 64, n0 = blockIdx.x * 64;
    int lane = t & 63, w = t >> 6, quad = lane >> 4, l16 = lane & 15;
    int srow = t >> 2, sc = (t & 3) * 8;
    f4 acc[4];
    for (int n = 0; n < 4; n++) acc[n] = (f4){0.f, 0.f, 0.f, 0.f};
    const int nk = K >> 5;
    for (int kt = 0; kt < nk; kt++) {
        *(short8*)&As[srow * 40 + sc] = *(const short8*)&A[(size_t)(m0 + srow) * K + kt * 32 + sc];
        *(short8*)&Bs[srow * 40 + sc] = *(const short8*)&W[(size_t)(n0 + srow) * K + kt * 32 + sc];
        __syncthreads();
        short8 a = *(const short8*)&As[(w * 16 + l16) * 40 + quad * 8];
        for (int n = 0; n < 4; n++) {
            short8 b = *(const short8*)&Bs[(n * 16 + l16) * 40 + quad * 8];
            acc[n] = __builtin_amdgcn_mfma_f32_16x16x32_bf16(a, b, acc[n], 0, 0, 0);
        }
        __syncthreads();
    }
    for (int n = 0; n < 4; n++)
        for (int r = 0; r < 4; r++) {
            int row = m0 + w * 16 + quad * 4 + r;
            int col = n0 + n * 16 + l16;
            float v = acc[n][r];
            if (OUT_BF16) ((u16*)Cout)[(size_t)row * N + col] = f2bf(v);
            else          ((float*)Cout)[(size_t)row * N + col] = v;
        }
}

// ---------------- RoPE in-place on bf16 buffer [B,S,nh,HD] ----------------
__global__ void rope_kernel(u16* __restrict__ qk, const float* __restrict__ freqs, int nh, int total) {
    int i = blockIdx.x * blockDim.x + threadIdx.x;  // one thread per (even,odd) pair
    if (i >= total) return;
    int hd2 = i & 63;
    int rest = i >> 6;             // (b*S+s)*nh + h
    int s = (rest / nh) & (S_ - 1);
    float c = freqs[(s * 64 + hd2) * 2 + 0];
    float sn = freqs[(s * 64 + hd2) * 2 + 1];
    ushort2 v = ((ushort2*)qk)[i];
    float x0 = bf2f(v.x), x1 = bf2f(v.y);
    ushort2 o;
    o.x = f2bf(x0 * c - x1 * sn);
    o.y = f2bf(x0 * sn + x1 * c);
    ((ushort2*)qk)[i] = o;
}

// ---------------- V transpose: [B,S,KVH,HD] -> [B,KVH,HD,S] ----------------
__global__ void transpose_v(const u16* __restrict__ Vb, u16* __restrict__ Vt) {
    int i = blockIdx.x * blockDim.x + threadIdx.x;
    if (i >= B_ * S_ * KVH_ * HD_) return;
    int col = i & 511;          // kvh*128+hd
    int row = i >> 9;           // b*S+s
    int b = row >> 11, s = row & (S_ - 1);
    Vt[((size_t)(b * KVH_ * HD_ + col)) * S_ + s] = Vb[i];
}

// ---------------- Flash attention: block = (qt, h, b), 4 waves x 16 q-rows ----------------
__global__ __launch_bounds__(256) void attn_kernel(const u16* __restrict__ Qb,
                                                   const u16* __restrict__ Kb,
                                                   const u16* __restrict__ Vt,
                                                   u16* __restrict__ Ob) {
    __shared__ u16 Ks[64 * 136];   // [kpos][hd], pad 128->136
    __shared__ u16 Vs[128 * 72];   // [hd][kpos], pad 64->72
    __shared__ u16 Ps[4 * 16 * 72];// per-wave P tile [16][64] pad->72
    int qt = blockIdx.x, h = blockIdx.y, b = blockIdx.z;
    int kvh = h >> 2;
    int t = threadIdx.x, lane = t & 63, w = t >> 6, quad = lane >> 4, l16 = lane & 15;
    const float scale = 0.08838834764831845f;  // 1/sqrt(128)

    // Q fragments (A-operand layout): row = lane&15 within wave's 16 rows
    short8 qf[4];
    {
        const u16* qp = Qb + ((size_t)(b * S_ + qt * 64 + w * 16 + l16)) * (H_ * HD_) + h * HD_ + quad * 8;
        for (int c = 0; c < 4; c++) qf[c] = *(const short8*)(qp + c * 32);
    }
    float m_i[4], l_i[4];
    f4 o[8];
    for (int r = 0; r < 4; r++) { m_i[r] = -1e30f; l_i[r] = 0.f; }
    for (int n = 0; n < 8; n++) o[n] = (f4){0.f, 0.f, 0.f, 0.f};

    for (int kt = 0; kt <= qt; kt++) {
        // stage K tile [64][128]
        for (int i = 0; i < 4; i++) {
            int chunk = t + i * 256;
            int row = chunk >> 4, c = chunk & 15;
            *(short8*)&Ks[row * 136 + c * 8] =
                *(const short8*)&Kb[((size_t)(b * S_ + kt * 64 + row)) * (KVH_ * HD_) + kvh * HD_ + c * 8];
        }
        // stage V tile transposed [128][64]
        for (int i = 0; i < 4; i++) {
            int chunk = t + i * 256;
            int hd = chunk >> 3, c = chunk & 7;
            *(short8*)&Vs[hd * 72 + c * 8] =
                *(const short8*)&Vt[((size_t)((b * KVH_ + kvh) * HD_ + hd)) * S_ + kt * 64 + c * 8];
        }
        __syncthreads();

        // scores: S = Q @ K^T, 4 n-tiles of 16 cols, K-dim = 128 in 4 chunks
        f4 sc4[4];
        for (int n = 0; n < 4; n++) sc4[n] = (f4){0.f, 0.f, 0.f, 0.f};
        for (int n = 0; n < 4; n++)
            for (int c = 0; c < 4; c++) {
                short8 bfr = *(const short8*)&Ks[(n * 16 + l16) * 136 + c * 32 + quad * 8];
                sc4[n] = __builtin_amdgcn_mfma_f32_16x16x32_bf16(qf[c], bfr, sc4[n], 0, 0, 0);
            }
        // scale + causal mask. D layout: col=l16 (k pos), row=quad*4+r (q row)
        int qrow_off = qt * 64 + w * 16 + quad * 4;
        for (int n = 0; n < 4; n++) {
            int colg = kt * 64 + n * 16 + l16;
            for (int r = 0; r < 4; r++) {
                float v = sc4[n][r] * scale;
                sc4[n][r] = (colg <= qrow_off + r) ? v : -1e30f;
            }
        }
        // row max across 16 lanes of the quad
        float alpha[4];
        for (int r = 0; r < 4; r++) {
            float mx = fmaxf(fmaxf(sc4[0][r], sc4[1][r]), fmaxf(sc4[2][r], sc4[3][r]));
            for (int off = 1; off < 16; off <<= 1)
                mx = fmaxf(mx, __shfl_xor(mx, off, 64));
            float mn = fmaxf(m_i[r], mx);
            alpha[r] = __expf(m_i[r] - mn);
            m_i[r] = mn;
        }
        // P = exp(S - m), row sums
        float rsum[4] = {0.f, 0.f, 0.f, 0.f};
        for (int n = 0; n < 4; n++)
            for (int r = 0; r < 4; r++) {
                float p = __expf(sc4[n][r] - m_i[r]);
                sc4[n][r] = p;
                rsum[r] += p;
            }
        for (int r = 0; r < 4; r++) {
            float sm = rsum[r];
            for (int off = 1; off < 16; off <<= 1)
                sm += __shfl_xor(sm, off, 64);
            l_i[r] = l_i[r] * alpha[r] + sm;
        }
        // rescale O accumulator
        for (int n = 0; n < 8; n++)
            for (int r = 0; r < 4; r++) o[n][r] *= alpha[r];
        // write P (bf16) to per-wave LDS region: C-layout -> memory [row][col]
        for (int n = 0; n < 4; n++)
            for (int r = 0; r < 4; r++)
                Ps[(w * 16 + quad * 4 + r) * 72 + n * 16 + l16] = f2bf(sc4[n][r]);
        __asm__ volatile("s_waitcnt lgkmcnt(0)" ::: "memory");
        // O += P @ V  (P read back in A-operand layout; V in B-operand layout)
        for (int kc = 0; kc < 2; kc++) {
            short8 af = *(const short8*)&Ps[(w * 16 + l16) * 72 + kc * 32 + quad * 8];
            for (int nt = 0; nt < 8; nt++) {
                short8 bfr = *(const short8*)&Vs[(nt * 16 + l16) * 72 + kc * 32 + quad * 8];
                o[nt] = __builtin_amdgcn_mfma_f32_16x16x32_bf16(af, bfr, o[nt], 0, 0, 0);
            }
        }
        __syncthreads();
    }
    // epilogue: O / l -> attn output bf16 [B,S,H*HD]
    for (int nt = 0; nt < 8; nt++)
        for (int r = 0; r < 4; r++) {
            int qrow = qt * 64 + w * 16 + quad * 4 + r;
            Ob[((size_t)(b * S_ + qrow)) * (H_ * HD_) + h * HD_ + nt * 16 + l16] = f2bf(o[nt][r] / l_i[r]);
        }
}

extern "C" void kernel_launch(void* const* d_in, const int* in_sizes, int n_in,
                              void* d_out, int out_size, void* d_ws, size_t ws_size,
                              hipStream_t stream) {
    const float* x     = (const float*)d_in[0];
    const float* freqs = (const float*)d_in[1];
    const float* wq    = (const float*)d_in[2];
    const float* wk    = (const float*)d_in[3];
    const float* wv    = (const float*)d_in[4];
    const float* wo    = (const float*)d_in[5];
    float* out = (float*)d_out;

    char* p = (char*)d_ws;
    u16* xb   = (u16*)p; p += (size_t)4096 * 2048 * 2;
    u16* wqb  = (u16*)p; p += (size_t)2048 * 2048 * 2;
    u16* wkb  = (u16*)p; p += (size_t)512 * 2048 * 2;
    u16* wvb  = (u16*)p; p += (size_t)512 * 2048 * 2;
    u16* wob  = (u16*)p; p += (size_t)2048 * 2048 * 2;
    u16* Qb   = (u16*)p; p += (size_t)4096 * 2048 * 2;
    u16* Kb   = (u16*)p; p += (size_t)4096 * 512 * 2;
    u16* Vb   = (u16*)p; p += (size_t)4096 * 512 * 2;
    u16* Vtb  = (u16*)p; p += (size_t)4096 * 512 * 2;
    u16* attnb= (u16*)p; p += (size_t)4096 * 2048 * 2;

    // casts
    cast4_kernel<<<8192, 256, 0, stream>>>(x, xb, 2097152);
    cast4_kernel<<<4096, 256, 0, stream>>>(wq, wqb, 1048576);
    cast4_kernel<<<1024, 256, 0, stream>>>(wk, wkb, 262144);
    cast4_kernel<<<1024, 256, 0, stream>>>(wv, wvb, 262144);
    cast4_kernel<<<4096, 256, 0, stream>>>(wo, wob, 1048576);

    // QKV projections
    gemm_bt<true><<<dim3(32, 64), 256, 0, stream>>>(xb, wqb, Qb, 4096, 2048, 2048);
    gemm_bt<true><<<dim3(8, 64), 256, 0, stream>>>(xb, wkb, Kb, 4096, 512, 2048);
    gemm_bt<true><<<dim3(8, 64), 256, 0, stream>>>(xb, wvb, Vb, 4096, 512, 2048);

    // RoPE (in place) on Q and K
    rope_kernel<<<16384, 256, 0, stream>>>(Qb, freqs, H_, B_ * S_ * H_ * 64);
    rope_kernel<<<4096, 256, 0, stream>>>(Kb, freqs, KVH_, B_ * S_ * KVH_ * 64);

    // V transpose for PV B-operand layout
    transpose_v<<<8192, 256, 0, stream>>>(Vb, Vtb);

    // flash attention
    attn_kernel<<<dim3(32, 16, 2), 256, 0, stream>>>(Qb, Kb, Vtb, attnb);

    // output projection -> fp32 out
    gemm_bt<false><<<dim3(32, 64), 256, 0, stream>>>(attnb, wob, out, 4096, 2048, 2048);
}

// Round 2
// 522.784 us; speedup vs baseline: 1.3500x; 1.3500x over previous
//
#include <hip/hip_runtime.h>
#include <stdint.h>

#define B_ 2
#define S_ 2048
#define DIM_ 2048
#define H_ 16
#define KVH_ 4
#define HD_ 128

typedef short short8 __attribute__((ext_vector_type(8)));
typedef float f4 __attribute__((ext_vector_type(4)));
typedef unsigned short u16;

__device__ __forceinline__ float bf2f(u16 u) {
    union { unsigned int i; float f; } c; c.i = ((unsigned int)u) << 16; return c.f;
}
__device__ __forceinline__ u16 f2bf(float f) {
    union { float f; unsigned int i; } c; c.f = f;
    return (u16)((c.i + 0x7fffu + ((c.i >> 16) & 1u)) >> 16);
}

// async global->LDS, 16B per lane; LDS dest must be wave-uniform (HW adds lane*16)
#define GLDS16(gp, lp) \
    __builtin_amdgcn_global_load_lds((const __attribute__((address_space(1))) unsigned int*)(gp), \
                                     (__attribute__((address_space(3))) unsigned int*)(lp), 16, 0, 0)

// ---------------- fp32 -> bf16 cast ----------------
__global__ void cast4_kernel(const float* __restrict__ in, u16* __restrict__ out, int n4) {
    int i = blockIdx.x * blockDim.x + threadIdx.x;
    if (i < n4) {
        float4 v = ((const float4*)in)[i];
        ushort4 o;
        o.x = f2bf(v.x); o.y = f2bf(v.y); o.z = f2bf(v.z); o.w = f2bf(v.w);
        ((ushort4*)out)[i] = o;
    }
}

// ---------------- GEMM: C[M,N] = A[M,K] @ W[N,K]^T, m97 structure ----------------
// 128x128 tile, BK=32, 4 waves in 2x2, each wave 4x4 subtiles of 16x16.
template<bool OUT_BF16>
__global__ __launch_bounds__(256) void gemm_bt(const u16* __restrict__ A,
                                               const u16* __restrict__ W,
                                               void* __restrict__ Cout,
                                               int M, int N, int K) {
    __shared__ u16 As[128 * 32];  // row-major, no padding (global_load_lds lane order)
    __shared__ u16 Bs[128 * 32];
    int t = threadIdx.x, lane = t & 63, w = t >> 6;
    int quad = lane >> 4, l16 = lane & 15;
    int wm = w & 1, wn = w >> 1;
    size_t m0 = (size_t)blockIdx.y * 128, n0 = (size_t)blockIdx.x * 128;

    // staging: wave w stages chunks {2w, 2w+1} of both A and B tiles
    int c0 = w * 2;
    int ar = c0 * 16 + (lane >> 2);      // tile row for chunk c0
    int ac = (lane & 3) * 8;             // col within BK=32
    const u16* Abase = A + (m0 + ar) * (size_t)K + ac;
    const u16* Bbase = W + (n0 + ar) * (size_t)K + ac;
    u16* Adst = As + c0 * 512;           // wave-uniform
    u16* Bdst = Bs + c0 * 512;

    f4 acc[4][4];
    #pragma unroll
    for (int i = 0; i < 4; i++)
        #pragma unroll
        for (int j = 0; j < 4; j++) acc[i][j] = (f4){0.f, 0.f, 0.f, 0.f};

    int nk = K >> 5;
    for (int kt = 0; kt < nk; kt++) {
        const u16* ga = Abase + kt * 32;
        const u16* gb = Bbase + kt * 32;
        GLDS16(ga, Adst);
        GLDS16(ga + 16 * (size_t)K, Adst + 512);
        GLDS16(gb, Bdst);
        GLDS16(gb + 16 * (size_t)K, Bdst + 512);
        __syncthreads();
        short8 a[4], b[4];
        #pragma unroll
        for (int i = 0; i < 4; i++) a[i] = *(const short8*)&As[(wm * 64 + i * 16 + l16) * 32 + quad * 8];
        #pragma unroll
        for (int j = 0; j < 4; j++) b[j] = *(const short8*)&Bs[(wn * 64 + j * 16 + l16) * 32 + quad * 8];
        #pragma unroll
        for (int i = 0; i < 4; i++)
            #pragma unroll
            for (int j = 0; j < 4; j++)
                acc[i][j] = __builtin_amdgcn_mfma_f32_16x16x32_bf16(a[i], b[j], acc[i][j], 0, 0, 0);
        __syncthreads();
    }
    #pragma unroll
    for (int i = 0; i < 4; i++) {
        size_t row = m0 + wm * 64 + i * 16 + quad * 4;
        #pragma unroll
        for (int j = 0; j < 4; j++) {
            size_t col = n0 + wn * 64 + j * 16 + l16;
            #pragma unroll
            for (int r = 0; r < 4; r++) {
                if (OUT_BF16) ((u16*)Cout)[(row + r) * N + col] = f2bf(acc[i][j][r]);
                else          ((float*)Cout)[(row + r) * N + col] = acc[i][j][r];
            }
        }
    }
}

// ---------------- RoPE in-place on QKV buffer [4096][3072] (Q cols 0..2047, K cols 2048..2559) ----------------
__global__ void rope_kernel(u16* __restrict__ QKV, const float* __restrict__ freqs) {
    int pc = blockIdx.x * 256 + threadIdx.x;   // pair index 0..1279 within row
    int row = blockIdx.y;                      // 0..4095
    int s = row & (S_ - 1);
    int hd2 = pc & 63;
    float2 cs = ((const float2*)freqs)[s * 64 + hd2];
    ushort2* pp = (ushort2*)(QKV + (size_t)row * 3072);
    ushort2 v = pp[pc];
    float x0 = bf2f(v.x), x1 = bf2f(v.y);
    ushort2 ov;
    ov.x = f2bf(x0 * cs.x - x1 * cs.y);
    ov.y = f2bf(x0 * cs.y + x1 * cs.x);
    pp[pc] = ov;
}

// ---------------- V transpose: QKV V-region -> Vt[B,KVH,HD,S] ----------------
__global__ __launch_bounds__(256) void transpose_v(const u16* __restrict__ QKV, u16* __restrict__ Vt) {
    __shared__ u16 L[64 * 72];
    int s0 = blockIdx.x * 64, hd0 = blockIdx.y * 64;
    int bk = blockIdx.z; int b = bk >> 2, kvh = bk & 3;
    int t = threadIdx.x;
    const u16* src = QKV + 2560 + kvh * 128 + hd0;
    #pragma unroll
    for (int p = 0; p < 2; p++) {
        int idx = t + p * 256;
        int r = idx >> 3, c = idx & 7;
        *(short8*)&L[r * 72 + c * 8] = *(const short8*)(src + (size_t)(b * S_ + s0 + r) * 3072 + c * 8);
    }
    __syncthreads();
    u16* dst = Vt + ((size_t)(b * KVH_ + kvh) * HD_ + hd0) * S_ + s0;
    #pragma unroll
    for (int p = 0; p < 2; p++) {
        int idx = t + p * 256;
        int r = idx >> 3, c = idx & 7;   // r = hd row, c*8 = s chunk
        short8 v;
        #pragma unroll
        for (int j = 0; j < 8; j++) v[j] = (short)L[(c * 8 + j) * 72 + r];
        *(short8*)(dst + (size_t)r * S_ + c * 8) = v;
    }
}

// ---------------- Flash attention: block=(b,kvh,qt16), 4 waves = 4 GQA heads, no barriers ----------------
__global__ __launch_bounds__(256) void attn_kernel(const u16* __restrict__ QKV,
                                                   const u16* __restrict__ Vt,
                                                   u16* __restrict__ Ob) {
    __shared__ u16 Ps[4 * 16 * 72];   // per-wave P C->A transform region
    int bk = blockIdx.x;              // b*KVH + kvh
    int b = bk >> 2, kvh = bk & 3;
    int qt = 127 - blockIdx.y;        // descending work order
    int t = threadIdx.x, lane = t & 63, w = t >> 6, quad = lane >> 4, l16 = lane & 15;
    int h = kvh * 4 + w;              // this wave's q-head
    const float kscale = 0.12753102f; // (1/sqrt(128)) * log2(e)  -> exp2 domain

    // Q fragments (A-layout): m = l16, k = c*32 + quad*8
    short8 qf[4];
    {
        const u16* qp = QKV + ((size_t)(b * S_ + qt * 16 + l16)) * 3072 + h * HD_ + quad * 8;
        #pragma unroll
        for (int c = 0; c < 4; c++) qf[c] = *(const short8*)(qp + c * 32);
    }
    float m_i[4], l_i[4];
    f4 o[8];
    #pragma unroll
    for (int r = 0; r < 4; r++) { m_i[r] = -1e30f; l_i[r] = 0.f; }
    #pragma unroll
    for (int n = 0; n < 8; n++) o[n] = (f4){0.f, 0.f, 0.f, 0.f};

    const u16* Kb = QKV + 2048 + kvh * HD_;
    const u16* Vb = Vt + ((size_t)(b * KVH_ + kvh)) * HD_ * S_;
    u16* P = Ps + w * 16 * 72;
    int nkt = (qt >> 2) + 1;

    for (int kt = 0; kt < nkt; kt++) {
        // scores: QK^T, K B-frags direct from global (L1-shared across the 4 waves)
        f4 sc[4];
        #pragma unroll
        for (int n = 0; n < 4; n++) sc[n] = (f4){0.f, 0.f, 0.f, 0.f};
        #pragma unroll
        for (int n = 0; n < 4; n++) {
            const u16* kp = Kb + ((size_t)(b * S_ + kt * 64 + n * 16 + l16)) * 3072 + quad * 8;
            short8 k0 = *(const short8*)(kp);
            short8 k1 = *(const short8*)(kp + 32);
            short8 k2 = *(const short8*)(kp + 64);
            short8 k3 = *(const short8*)(kp + 96);
            sc[n] = __builtin_amdgcn_mfma_f32_16x16x32_bf16(qf[0], k0, sc[n], 0, 0, 0);
            sc[n] = __builtin_amdgcn_mfma_f32_16x16x32_bf16(qf[1], k1, sc[n], 0, 0, 0);
            sc[n] = __builtin_amdgcn_mfma_f32_16x16x32_bf16(qf[2], k2, sc[n], 0, 0, 0);
            sc[n] = __builtin_amdgcn_mfma_f32_16x16x32_bf16(qf[3], k3, sc[n], 0, 0, 0);
        }
        // scale (exp2 domain) + causal mask. D: row=quad*4+r, col=n*16+l16
        int qrow0 = qt * 16 + quad * 4;
        #pragma unroll
        for (int n = 0; n < 4; n++) {
            int colg = kt * 64 + n * 16 + l16;
            #pragma unroll
            for (int r = 0; r < 4; r++) {
                float v = sc[n][r] * kscale;
                sc[n][r] = (colg <= qrow0 + r) ? v : -1e30f;
            }
        }
        // online softmax (per-quad rows, 16-lane reductions)
        float alpha[4];
        #pragma unroll
        for (int r = 0; r < 4; r++) {
            float mx = fmaxf(fmaxf(sc[0][r], sc[1][r]), fmaxf(sc[2][r], sc[3][r]));
            #pragma unroll
            for (int off = 1; off < 16; off <<= 1) mx = fmaxf(mx, __shfl_xor(mx, off, 64));
            float mn = fmaxf(m_i[r], mx);
            alpha[r] = exp2f(m_i[r] - mn);
            m_i[r] = mn;
        }
        float rs[4] = {0.f, 0.f, 0.f, 0.f};
        #pragma unroll
        for (int n = 0; n < 4; n++)
            #pragma unroll
            for (int r = 0; r < 4; r++) {
                float p = exp2f(sc[n][r] - m_i[r]);
                sc[n][r] = p;
                rs[r] += p;
            }
        #pragma unroll
        for (int r = 0; r < 4; r++) {
            float sm = rs[r];
            #pragma unroll
            for (int off = 1; off < 16; off <<= 1) sm += __shfl_xor(sm, off, 64);
            l_i[r] = l_i[r] * alpha[r] + sm;
        }
        #pragma unroll
        for (int nt = 0; nt < 8; nt++)
            #pragma unroll
            for (int r = 0; r < 4; r++) o[nt][r] *= alpha[r];
        // P: C-layout -> per-wave LDS -> A-layout (same wave, waitcnt only)
        #pragma unroll
        for (int n = 0; n < 4; n++)
            #pragma unroll
            for (int r = 0; r < 4; r++)
                P[(quad * 4 + r) * 72 + n * 16 + l16] = f2bf(sc[n][r]);
        __asm__ volatile("s_waitcnt lgkmcnt(0)" ::: "memory");
        // O += P @ V, V B-frags direct from Vt (contiguous along S)
        #pragma unroll
        for (int kc = 0; kc < 2; kc++) {
            short8 af = *(const short8*)&P[l16 * 72 + kc * 32 + quad * 8];
            #pragma unroll
            for (int nt = 0; nt < 8; nt++) {
                const u16* vp = Vb + ((size_t)(nt * 16 + l16)) * S_ + kt * 64 + kc * 32 + quad * 8;
                short8 bf = *(const short8*)vp;
                o[nt] = __builtin_amdgcn_mfma_f32_16x16x32_bf16(af, bf, o[nt], 0, 0, 0);
            }
        }
    }
    // epilogue
    float rl[4];
    #pragma unroll
    for (int r = 0; r < 4; r++) rl[r] = 1.0f / l_i[r];
    #pragma unroll
    for (int nt = 0; nt < 8; nt++)
        #pragma unroll
        for (int r = 0; r < 4; r++) {
            size_t row = (size_t)b * S_ + qt * 16 + quad * 4 + r;
            Ob[row * 2048 + h * HD_ + nt * 16 + l16] = f2bf(o[nt][r] * rl[r]);
        }
}

extern "C" void kernel_launch(void* const* d_in, const int* in_sizes, int n_in,
                              void* d_out, int out_size, void* d_ws, size_t ws_size,
                              hipStream_t stream) {
    const float* x     = (const float*)d_in[0];
    const float* freqs = (const float*)d_in[1];
    const float* wq    = (const float*)d_in[2];
    const float* wk    = (const float*)d_in[3];
    const float* wv    = (const float*)d_in[4];
    const float* wo    = (const float*)d_in[5];
    float* out = (float*)d_out;

    char* p = (char*)d_ws;
    u16* xb    = (u16*)p; p += (size_t)4096 * 2048 * 2;   // 16MB
    u16* wqkvb = (u16*)p; p += (size_t)3072 * 2048 * 2;   // 12MB (wq | wk | wv concat along N)
    u16* wob   = (u16*)p; p += (size_t)2048 * 2048 * 2;   // 8MB
    u16* QKVb  = (u16*)p; p += (size_t)4096 * 3072 * 2;   // 24MB
    u16* Vtb   = (u16*)p; p += (size_t)8 * 128 * 2048 * 2;// 4MB
    u16* attnb = xb;  // reuse: x not needed after QKV GEMM

    // casts
    cast4_kernel<<<8192, 256, 0, stream>>>(x, xb, 2097152);
    cast4_kernel<<<4096, 256, 0, stream>>>(wq, wqkvb, 1048576);
    cast4_kernel<<<1024, 256, 0, stream>>>(wk, wqkvb + (size_t)2048 * 2048, 262144);
    cast4_kernel<<<1024, 256, 0, stream>>>(wv, wqkvb + (size_t)2560 * 2048, 262144);
    cast4_kernel<<<4096, 256, 0, stream>>>(wo, wob, 1048576);

    // fused QKV projection: [4096,2048] @ [3072,2048]^T -> [4096,3072]
    gemm_bt<true><<<dim3(24, 32), 256, 0, stream>>>(xb, wqkvb, QKVb, 4096, 3072, 2048);

    // RoPE in-place on Q (cols 0..2047) and K (cols 2048..2559)
    rope_kernel<<<dim3(5, 4096), 256, 0, stream>>>(QKVb, freqs);

    // V transpose for PV B-operand layout
    transpose_v<<<dim3(32, 2, 8), 256, 0, stream>>>(QKVb, Vtb);

    // flash attention (no intra-block barriers)
    attn_kernel<<<dim3(8, 128), 256, 0, stream>>>(QKVb, Vtb, attnb);

    // output projection -> fp32
    gemm_bt<false><<<dim3(16, 32), 256, 0, stream>>>(attnb, wob, out, 4096, 2048, 2048);
}

// Round 3
// 416.298 us; speedup vs baseline: 1.6953x; 1.2558x over previous
//
#include <hip/hip_runtime.h>
#include <stdint.h>

#define B_ 2
#define S_ 2048
#define DIM_ 2048
#define H_ 16
#define KVH_ 4
#define HD_ 128

typedef short short8 __attribute__((ext_vector_type(8)));
typedef float f4 __attribute__((ext_vector_type(4)));
typedef unsigned short u16;

__device__ __forceinline__ float bf2f(u16 u) {
    union { unsigned int i; float f; } c; c.i = ((unsigned int)u) << 16; return c.f;
}
__device__ __forceinline__ u16 f2bf(float f) {
    union { float f; unsigned int i; } c; c.f = f;
    return (u16)((c.i + 0x7fffu + ((c.i >> 16) & 1u)) >> 16);
}

// async global->LDS, 16B per lane; LDS dest is wave-uniform base + lane*16
#define GLDS16(gp, lp) \
    __builtin_amdgcn_global_load_lds((const __attribute__((address_space(1))) unsigned int*)(gp), \
                                     (__attribute__((address_space(3))) unsigned int*)(lp), 16, 0, 0)

// ---------------- fp32 -> bf16 cast ----------------
__global__ void cast4_kernel(const float* __restrict__ in, u16* __restrict__ out, int n4) {
    int i = blockIdx.x * blockDim.x + threadIdx.x;
    if (i < n4) {
        float4 v = ((const float4*)in)[i];
        ushort4 o;
        o.x = f2bf(v.x); o.y = f2bf(v.y); o.z = f2bf(v.z); o.w = f2bf(v.w);
        ((ushort4*)out)[i] = o;
    }
}

// ---------------- GEMM: C[M,N] = A[M,K] @ W[N,K]^T, m97 structure ----------------
template<bool OUT_BF16>
__global__ __launch_bounds__(256) void gemm_bt(const u16* __restrict__ A,
                                               const u16* __restrict__ W,
                                               void* __restrict__ Cout,
                                               int M, int N, int K) {
    __shared__ u16 As[128 * 32];
    __shared__ u16 Bs[128 * 32];
    int t = threadIdx.x, lane = t & 63, w = t >> 6;
    int quad = lane >> 4, l16 = lane & 15;
    int wm = w & 1, wn = w >> 1;
    size_t m0 = (size_t)blockIdx.y * 128, n0 = (size_t)blockIdx.x * 128;

    int c0 = w * 2;
    int ar = c0 * 16 + (lane >> 2);
    int ac = (lane & 3) * 8;
    const u16* Abase = A + (m0 + ar) * (size_t)K + ac;
    const u16* Bbase = W + (n0 + ar) * (size_t)K + ac;
    u16* Adst = As + c0 * 512;
    u16* Bdst = Bs + c0 * 512;

    f4 acc[4][4];
    #pragma unroll
    for (int i = 0; i < 4; i++)
        #pragma unroll
        for (int j = 0; j < 4; j++) acc[i][j] = (f4){0.f, 0.f, 0.f, 0.f};

    int nk = K >> 5;
    for (int kt = 0; kt < nk; kt++) {
        const u16* ga = Abase + kt * 32;
        const u16* gb = Bbase + kt * 32;
        GLDS16(ga, Adst);
        GLDS16(ga + 16 * (size_t)K, Adst + 512);
        GLDS16(gb, Bdst);
        GLDS16(gb + 16 * (size_t)K, Bdst + 512);
        __syncthreads();
        short8 a[4], b[4];
        #pragma unroll
        for (int i = 0; i < 4; i++) a[i] = *(const short8*)&As[(wm * 64 + i * 16 + l16) * 32 + quad * 8];
        #pragma unroll
        for (int j = 0; j < 4; j++) b[j] = *(const short8*)&Bs[(wn * 64 + j * 16 + l16) * 32 + quad * 8];
        #pragma unroll
        for (int i = 0; i < 4; i++)
            #pragma unroll
            for (int j = 0; j < 4; j++)
                acc[i][j] = __builtin_amdgcn_mfma_f32_16x16x32_bf16(a[i], b[j], acc[i][j], 0, 0, 0);
        __syncthreads();
    }
    #pragma unroll
    for (int i = 0; i < 4; i++) {
        size_t row = m0 + wm * 64 + i * 16 + quad * 4;
        #pragma unroll
        for (int j = 0; j < 4; j++) {
            size_t col = n0 + wn * 64 + j * 16 + l16;
            #pragma unroll
            for (int r = 0; r < 4; r++) {
                if (OUT_BF16) ((u16*)Cout)[(row + r) * N + col] = f2bf(acc[i][j][r]);
                else          ((float*)Cout)[(row + r) * N + col] = acc[i][j][r];
            }
        }
    }
}

// ---------------- RoPE in-place on QKV buffer [4096][3072] ----------------
__global__ void rope_kernel(u16* __restrict__ QKV, const float* __restrict__ freqs) {
    int pc = blockIdx.x * 256 + threadIdx.x;   // pair index 0..1279
    int row = blockIdx.y;
    int s = row & (S_ - 1);
    int hd2 = pc & 63;
    float2 cs = ((const float2*)freqs)[s * 64 + hd2];
    ushort2* pp = (ushort2*)(QKV + (size_t)row * 3072);
    ushort2 v = pp[pc];
    float x0 = bf2f(v.x), x1 = bf2f(v.y);
    ushort2 ov;
    ov.x = f2bf(x0 * cs.x - x1 * cs.y);
    ov.y = f2bf(x0 * cs.y + x1 * cs.x);
    pp[pc] = ov;
}

// ---------------- pack K into MFMA B-fragment order ----------------
// Kp[bk][kt][fid=n*4+c][lane][8] = K[b, s=kt*64+n*16+l16, kvh, hd=c*32+quad*8+j]
__global__ __launch_bounds__(256) void pack_k(const u16* __restrict__ QKV, u16* __restrict__ Kp) {
    int gid = blockIdx.x * 256 + threadIdx.x;   // 262144
    int lane = gid & 63;
    int fid = (gid >> 6) & 15;
    int kt = (gid >> 10) & 31;
    int bk = gid >> 15;
    int b = bk >> 2, kvh = bk & 3;
    int n = fid >> 2, c = fid & 3;
    int l16 = lane & 15, quad = lane >> 4;
    int s = kt * 64 + n * 16 + l16;
    const u16* src = QKV + (size_t)(b * 2048 + s) * 3072 + 2048 + kvh * 128 + c * 32 + quad * 8;
    *(short8*)&Kp[(size_t)gid * 8] = *(const short8*)src;
}

// ---------------- pack V into MFMA B-fragment order (hd = n dim, kpos = k dim) ----------------
// Vp[bk][kt][fid=nt*2+kc][lane][8] = V[b, s=kt*64+kc*32+quad*8+j, kvh, hd=nt*16+l16]
__global__ __launch_bounds__(256) void pack_v(const u16* __restrict__ QKV, u16* __restrict__ Vp) {
    int gid = blockIdx.x * 256 + threadIdx.x;
    int lane = gid & 63;
    int fid = (gid >> 6) & 15;
    int kt = (gid >> 10) & 31;
    int bk = gid >> 15;
    int b = bk >> 2, kvh = bk & 3;
    int nt = fid >> 1, kc = fid & 1;
    int l16 = lane & 15, quad = lane >> 4;
    int hd = nt * 16 + l16;
    int s0 = kt * 64 + kc * 32 + quad * 8;
    const u16* src = QKV + (size_t)(b * 2048 + s0) * 3072 + 2560 + kvh * 128 + hd;
    short8 v;
    #pragma unroll
    for (int j = 0; j < 8; j++) v[j] = (short)src[(size_t)j * 3072];
    *(short8*)&Vp[(size_t)gid * 8] = v;
}

// ---------------- Flash attention: block=(bk, pair), 4 waves = 4 GQA heads ----------------
// Paired q-tiles (pr, 127-pr): every block does exactly ~33 k-tiles, shares staged K/V.
__global__ __launch_bounds__(256) void attn_kernel(const u16* __restrict__ QKV,
                                                   const u16* __restrict__ Kp,
                                                   const u16* __restrict__ Vp,
                                                   u16* __restrict__ Ob) {
    __shared__ u16 Ks[16 * 512];      // 16KB packed K tile
    __shared__ u16 Vs[16 * 512];      // 16KB packed V tile
    __shared__ u16 Ps[4 * 2 * 16 * 72]; // per-wave L/S P-transform regions
    int bk = blockIdx.x;
    int b = bk >> 2, kvh = bk & 3;
    int pr = blockIdx.y;              // 0..63
    int qtS = pr, qtL = 127 - pr;
    int nktS = (qtS >> 2) + 1, nktL = (qtL >> 2) + 1;
    int t = threadIdx.x, lane = t & 63, w = t >> 6, quad = lane >> 4, l16 = lane & 15;
    int h = kvh * 4 + w;
    const float kscale = 0.08838834764831845f * 1.4426950408889634f; // /sqrt(128) * log2e

    short8 qfL[4], qfS[4];
    {
        const u16* qpL = QKV + ((size_t)(b * S_ + qtL * 16 + l16)) * 3072 + h * HD_ + quad * 8;
        const u16* qpS = QKV + ((size_t)(b * S_ + qtS * 16 + l16)) * 3072 + h * HD_ + quad * 8;
        #pragma unroll
        for (int c = 0; c < 4; c++) { qfL[c] = *(const short8*)(qpL + c * 32); qfS[c] = *(const short8*)(qpS + c * 32); }
    }
    float mL[4], lL[4], mS[4], lS[4];
    f4 oL[8], oS[8];
    #pragma unroll
    for (int r = 0; r < 4; r++) { mL[r] = -1e30f; lL[r] = 0.f; mS[r] = -1e30f; lS[r] = 0.f; }
    #pragma unroll
    for (int n = 0; n < 8; n++) { oL[n] = (f4){0.f,0.f,0.f,0.f}; oS[n] = (f4){0.f,0.f,0.f,0.f}; }

    const u16* Kpb = Kp + (size_t)bk * 32 * 8192;
    const u16* Vpb = Vp + (size_t)bk * 32 * 8192;
    u16* PL = Ps + (w * 2 + 0) * 1152;
    u16* PS = Ps + (w * 2 + 1) * 1152;

    for (int kt = 0; kt < nktL; kt++) {
        // stage packed K,V tiles: wave w covers fragment ids w*4..w*4+3
        {
            const u16* ks = Kpb + (size_t)kt * 8192 + (w * 4) * 512 + lane * 8;
            const u16* vs = Vpb + (size_t)kt * 8192 + (w * 4) * 512 + lane * 8;
            #pragma unroll
            for (int i = 0; i < 4; i++) {
                GLDS16(ks + i * 512, &Ks[(w * 4 + i) * 512]);
                GLDS16(vs + i * 512, &Vs[(w * 4 + i) * 512]);
            }
        }
        __syncthreads();
        bool doS = (kt < nktS);

        f4 scL[4], scS[4];
        #pragma unroll
        for (int n = 0; n < 4; n++) { scL[n] = (f4){0.f,0.f,0.f,0.f}; scS[n] = (f4){0.f,0.f,0.f,0.f}; }
        #pragma unroll
        for (int n = 0; n < 4; n++) {
            short8 k0 = *(const short8*)&Ks[(n * 4 + 0) * 512 + lane * 8];
            short8 k1 = *(const short8*)&Ks[(n * 4 + 1) * 512 + lane * 8];
            short8 k2 = *(const short8*)&Ks[(n * 4 + 2) * 512 + lane * 8];
            short8 k3 = *(const short8*)&Ks[(n * 4 + 3) * 512 + lane * 8];
            scL[n] = __builtin_amdgcn_mfma_f32_16x16x32_bf16(qfL[0], k0, scL[n], 0, 0, 0);
            scL[n] = __builtin_amdgcn_mfma_f32_16x16x32_bf16(qfL[1], k1, scL[n], 0, 0, 0);
            scL[n] = __builtin_amdgcn_mfma_f32_16x16x32_bf16(qfL[2], k2, scL[n], 0, 0, 0);
            scL[n] = __builtin_amdgcn_mfma_f32_16x16x32_bf16(qfL[3], k3, scL[n], 0, 0, 0);
            if (doS) {
                scS[n] = __builtin_amdgcn_mfma_f32_16x16x32_bf16(qfS[0], k0, scS[n], 0, 0, 0);
                scS[n] = __builtin_amdgcn_mfma_f32_16x16x32_bf16(qfS[1], k1, scS[n], 0, 0, 0);
                scS[n] = __builtin_amdgcn_mfma_f32_16x16x32_bf16(qfS[2], k2, scS[n], 0, 0, 0);
                scS[n] = __builtin_amdgcn_mfma_f32_16x16x32_bf16(qfS[3], k3, scS[n], 0, 0, 0);
            }
        }

        // ---- online softmax, L tile ----
        {
            int qrow0 = qtL * 16 + quad * 4;
            if (kt == nktL - 1) {  // only last k-tile can be partially masked
                #pragma unroll
                for (int n = 0; n < 4; n++) {
                    int colg = kt * 64 + n * 16 + l16;
                    #pragma unroll
                    for (int r = 0; r < 4; r++)
                        scL[n][r] = (colg <= qrow0 + r) ? scL[n][r] * kscale : -1e30f;
                }
            } else {
                #pragma unroll
                for (int n = 0; n < 4; n++)
                    #pragma unroll
                    for (int r = 0; r < 4; r++) scL[n][r] *= kscale;
            }
            float alpha[4];
            #pragma unroll
            for (int r = 0; r < 4; r++) {
                float mx = fmaxf(fmaxf(scL[0][r], scL[1][r]), fmaxf(scL[2][r], scL[3][r]));
                #pragma unroll
                for (int off = 1; off < 16; off <<= 1) mx = fmaxf(mx, __shfl_xor(mx, off, 64));
                float mn = fmaxf(mL[r], mx);
                alpha[r] = exp2f(mL[r] - mn);
                mL[r] = mn;
            }
            float rs[4] = {0.f,0.f,0.f,0.f};
            #pragma unroll
            for (int n = 0; n < 4; n++)
                #pragma unroll
                for (int r = 0; r < 4; r++) {
                    float pv = exp2f(scL[n][r] - mL[r]);
                    scL[n][r] = pv;
                    rs[r] += pv;
                }
            #pragma unroll
            for (int r = 0; r < 4; r++) {
                float sm = rs[r];
                #pragma unroll
                for (int off = 1; off < 16; off <<= 1) sm += __shfl_xor(sm, off, 64);
                lL[r] = lL[r] * alpha[r] + sm;
            }
            #pragma unroll
            for (int nt = 0; nt < 8; nt++)
                #pragma unroll
                for (int r = 0; r < 4; r++) oL[nt][r] *= alpha[r];
            #pragma unroll
            for (int n = 0; n < 4; n++)
                #pragma unroll
                for (int r = 0; r < 4; r++)
                    PL[(quad * 4 + r) * 72 + n * 16 + l16] = f2bf(scL[n][r]);
        }
        // ---- online softmax, S tile ----
        if (doS) {
            int qrow0 = qtS * 16 + quad * 4;
            if (kt == nktS - 1) {
                #pragma unroll
                for (int n = 0; n < 4; n++) {
                    int colg = kt * 64 + n * 16 + l16;
                    #pragma unroll
                    for (int r = 0; r < 4; r++)
                        scS[n][r] = (colg <= qrow0 + r) ? scS[n][r] * kscale : -1e30f;
                }
            } else {
                #pragma unroll
                for (int n = 0; n < 4; n++)
                    #pragma unroll
                    for (int r = 0; r < 4; r++) scS[n][r] *= kscale;
            }
            float alpha[4];
            #pragma unroll
            for (int r = 0; r < 4; r++) {
                float mx = fmaxf(fmaxf(scS[0][r], scS[1][r]), fmaxf(scS[2][r], scS[3][r]));
                #pragma unroll
                for (int off = 1; off < 16; off <<= 1) mx = fmaxf(mx, __shfl_xor(mx, off, 64));
                float mn = fmaxf(mS[r], mx);
                alpha[r] = exp2f(mS[r] - mn);
                mS[r] = mn;
            }
            float rs[4] = {0.f,0.f,0.f,0.f};
            #pragma unroll
            for (int n = 0; n < 4; n++)
                #pragma unroll
                for (int r = 0; r < 4; r++) {
                    float pv = exp2f(scS[n][r] - mS[r]);
                    scS[n][r] = pv;
                    rs[r] += pv;
                }
            #pragma unroll
            for (int r = 0; r < 4; r++) {
                float sm = rs[r];
                #pragma unroll
                for (int off = 1; off < 16; off <<= 1) sm += __shfl_xor(sm, off, 64);
                lS[r] = lS[r] * alpha[r] + sm;
            }
            #pragma unroll
            for (int nt = 0; nt < 8; nt++)
                #pragma unroll
                for (int r = 0; r < 4; r++) oS[nt][r] *= alpha[r];
            #pragma unroll
            for (int n = 0; n < 4; n++)
                #pragma unroll
                for (int r = 0; r < 4; r++)
                    PS[(quad * 4 + r) * 72 + n * 16 + l16] = f2bf(scS[n][r]);
        }
        __asm__ volatile("s_waitcnt lgkmcnt(0)" ::: "memory");

        // ---- PV: O += P @ V ----
        short8 aL0 = *(const short8*)&PL[l16 * 72 + 0 + quad * 8];
        short8 aL1 = *(const short8*)&PL[l16 * 72 + 32 + quad * 8];
        short8 aS0, aS1;
        if (doS) {
            aS0 = *(const short8*)&PS[l16 * 72 + 0 + quad * 8];
            aS1 = *(const short8*)&PS[l16 * 72 + 32 + quad * 8];
        }
        #pragma unroll
        for (int nt = 0; nt < 8; nt++) {
            short8 v0 = *(const short8*)&Vs[(nt * 2 + 0) * 512 + lane * 8];
            short8 v1 = *(const short8*)&Vs[(nt * 2 + 1) * 512 + lane * 8];
            oL[nt] = __builtin_amdgcn_mfma_f32_16x16x32_bf16(aL0, v0, oL[nt], 0, 0, 0);
            oL[nt] = __builtin_amdgcn_mfma_f32_16x16x32_bf16(aL1, v1, oL[nt], 0, 0, 0);
            if (doS) {
                oS[nt] = __builtin_amdgcn_mfma_f32_16x16x32_bf16(aS0, v0, oS[nt], 0, 0, 0);
                oS[nt] = __builtin_amdgcn_mfma_f32_16x16x32_bf16(aS1, v1, oS[nt], 0, 0, 0);
            }
        }
        __syncthreads();
    }
    // epilogue
    float rlL[4], rlS[4];
    #pragma unroll
    for (int r = 0; r < 4; r++) { rlL[r] = 1.0f / lL[r]; rlS[r] = 1.0f / lS[r]; }
    #pragma unroll
    for (int nt = 0; nt < 8; nt++)
        #pragma unroll
        for (int r = 0; r < 4; r++) {
            size_t rowL = (size_t)b * S_ + qtL * 16 + quad * 4 + r;
            size_t rowS = (size_t)b * S_ + qtS * 16 + quad * 4 + r;
            Ob[rowL * 2048 + h * HD_ + nt * 16 + l16] = f2bf(oL[nt][r] * rlL[r]);
            Ob[rowS * 2048 + h * HD_ + nt * 16 + l16] = f2bf(oS[nt][r] * rlS[r]);
        }
}

extern "C" void kernel_launch(void* const* d_in, const int* in_sizes, int n_in,
                              void* d_out, int out_size, void* d_ws, size_t ws_size,
                              hipStream_t stream) {
    const float* x     = (const float*)d_in[0];
    const float* freqs = (const float*)d_in[1];
    const float* wq    = (const float*)d_in[2];
    const float* wk    = (const float*)d_in[3];
    const float* wv    = (const float*)d_in[4];
    const float* wo    = (const float*)d_in[5];
    float* out = (float*)d_out;

    char* p = (char*)d_ws;
    u16* xb    = (u16*)p; p += (size_t)4096 * 2048 * 2;   // 16MB
    u16* wqkvb = (u16*)p; p += (size_t)3072 * 2048 * 2;   // 12MB
    u16* wob   = (u16*)p; p += (size_t)2048 * 2048 * 2;   // 8MB
    u16* QKVb  = (u16*)p; p += (size_t)4096 * 3072 * 2;   // 24MB
    u16* Kpb   = (u16*)p; p += (size_t)8 * 32 * 8192 * 2; // 4MB
    u16* Vpb   = (u16*)p; p += (size_t)8 * 32 * 8192 * 2; // 4MB
    u16* attnb = xb;  // reuse

    cast4_kernel<<<8192, 256, 0, stream>>>(x, xb, 2097152);
    cast4_kernel<<<4096, 256, 0, stream>>>(wq, wqkvb, 1048576);
    cast4_kernel<<<1024, 256, 0, stream>>>(wk, wqkvb + (size_t)2048 * 2048, 262144);
    cast4_kernel<<<1024, 256, 0, stream>>>(wv, wqkvb + (size_t)2560 * 2048, 262144);
    cast4_kernel<<<4096, 256, 0, stream>>>(wo, wob, 1048576);

    gemm_bt<true><<<dim3(24, 32), 256, 0, stream>>>(xb, wqkvb, QKVb, 4096, 3072, 2048);

    rope_kernel<<<dim3(5, 4096), 256, 0, stream>>>(QKVb, freqs);

    pack_k<<<1024, 256, 0, stream>>>(QKVb, Kpb);
    pack_v<<<1024, 256, 0, stream>>>(QKVb, Vpb);

    attn_kernel<<<dim3(8, 64), 256, 0, stream>>>(QKVb, Kpb, Vpb, attnb);

    gemm_bt<false><<<dim3(16, 32), 256, 0, stream>>>(attnb, wob, out, 4096, 2048, 2048);
}

// Round 4
// 344.566 us; speedup vs baseline: 2.0482x; 1.2082x over previous
//
#include <hip/hip_runtime.h>
#include <stdint.h>

#define B_ 2
#define S_ 2048
#define DIM_ 2048
#define H_ 16
#define KVH_ 4
#define HD_ 128

typedef short short8 __attribute__((ext_vector_type(8)));
typedef float f4 __attribute__((ext_vector_type(4)));
typedef unsigned short u16;

__device__ __forceinline__ float bf2f(u16 u) {
    union { unsigned int i; float f; } c; c.i = ((unsigned int)u) << 16; return c.f;
}
__device__ __forceinline__ u16 f2bf(float f) {
    union { float f; unsigned int i; } c; c.f = f;
    return (u16)((c.i + 0x7fffu + ((c.i >> 16) & 1u)) >> 16);
}

// async global->LDS, 16B per lane; LDS dest is wave-uniform base + lane*16
#define GLDS16(gp, lp) \
    __builtin_amdgcn_global_load_lds((const __attribute__((address_space(1))) unsigned int*)(gp), \
                                     (__attribute__((address_space(3))) unsigned int*)(lp), 16, 0, 0)

// ---------------- fp32 -> bf16 cast ----------------
__global__ void cast4_kernel(const float* __restrict__ in, u16* __restrict__ out, int n4) {
    int i = blockIdx.x * blockDim.x + threadIdx.x;
    if (i < n4) {
        float4 v = ((const float4*)in)[i];
        ushort4 o;
        o.x = f2bf(v.x); o.y = f2bf(v.y); o.z = f2bf(v.z); o.w = f2bf(v.w);
        ((ushort4*)out)[i] = o;
    }
}

// ---------------- GEMM: C[M,N] = A[M,K] @ W[N,K]^T, m97 structure ----------------
template<bool OUT_BF16>
__global__ __launch_bounds__(256) void gemm_bt(const u16* __restrict__ A,
                                               const u16* __restrict__ W,
                                               void* __restrict__ Cout,
                                               int M, int N, int K) {
    __shared__ u16 As[128 * 32];
    __shared__ u16 Bs[128 * 32];
    int t = threadIdx.x, lane = t & 63, w = t >> 6;
    int quad = lane >> 4, l16 = lane & 15;
    int wm = w & 1, wn = w >> 1;
    size_t m0 = (size_t)blockIdx.y * 128, n0 = (size_t)blockIdx.x * 128;

    int c0 = w * 2;
    int ar = c0 * 16 + (lane >> 2);
    int ac = (lane & 3) * 8;
    const u16* Abase = A + (m0 + ar) * (size_t)K + ac;
    const u16* Bbase = W + (n0 + ar) * (size_t)K + ac;
    u16* Adst = As + c0 * 512;
    u16* Bdst = Bs + c0 * 512;

    f4 acc[4][4];
    #pragma unroll
    for (int i = 0; i < 4; i++)
        #pragma unroll
        for (int j = 0; j < 4; j++) acc[i][j] = (f4){0.f, 0.f, 0.f, 0.f};

    int nk = K >> 5;
    for (int kt = 0; kt < nk; kt++) {
        const u16* ga = Abase + kt * 32;
        const u16* gb = Bbase + kt * 32;
        GLDS16(ga, Adst);
        GLDS16(ga + 16 * (size_t)K, Adst + 512);
        GLDS16(gb, Bdst);
        GLDS16(gb + 16 * (size_t)K, Bdst + 512);
        __syncthreads();
        short8 a[4], b[4];
        #pragma unroll
        for (int i = 0; i < 4; i++) a[i] = *(const short8*)&As[(wm * 64 + i * 16 + l16) * 32 + quad * 8];
        #pragma unroll
        for (int j = 0; j < 4; j++) b[j] = *(const short8*)&Bs[(wn * 64 + j * 16 + l16) * 32 + quad * 8];
        #pragma unroll
        for (int i = 0; i < 4; i++)
            #pragma unroll
            for (int j = 0; j < 4; j++)
                acc[i][j] = __builtin_amdgcn_mfma_f32_16x16x32_bf16(a[i], b[j], acc[i][j], 0, 0, 0);
        __syncthreads();
    }
    #pragma unroll
    for (int i = 0; i < 4; i++) {
        size_t row = m0 + wm * 64 + i * 16 + quad * 4;
        #pragma unroll
        for (int j = 0; j < 4; j++) {
            size_t col = n0 + wn * 64 + j * 16 + l16;
            #pragma unroll
            for (int r = 0; r < 4; r++) {
                if (OUT_BF16) ((u16*)Cout)[(row + r) * N + col] = f2bf(acc[i][j][r]);
                else          ((float*)Cout)[(row + r) * N + col] = acc[i][j][r];
            }
        }
    }
}

// ---------------- RoPE in-place on QKV buffer [4096][3072] ----------------
__global__ void rope_kernel(u16* __restrict__ QKV, const float* __restrict__ freqs) {
    int pc = blockIdx.x * 256 + threadIdx.x;   // pair index 0..1279
    int row = blockIdx.y;
    int s = row & (S_ - 1);
    int hd2 = pc & 63;
    float2 cs = ((const float2*)freqs)[s * 64 + hd2];
    ushort2* pp = (ushort2*)(QKV + (size_t)row * 3072);
    ushort2 v = pp[pc];
    float x0 = bf2f(v.x), x1 = bf2f(v.y);
    ushort2 ov;
    ov.x = f2bf(x0 * cs.x - x1 * cs.y);
    ov.y = f2bf(x0 * cs.y + x1 * cs.x);
    pp[pc] = ov;
}

// ---------------- pack K into MFMA B-fragment order ----------------
// Kp[bk][kt][fid=n*4+c][lane][8] = K[b, s=kt*64+n*16+l16, kvh, hd=c*32+quad*8+j]
__global__ __launch_bounds__(256) void pack_k(const u16* __restrict__ QKV, u16* __restrict__ Kp) {
    int gid = blockIdx.x * 256 + threadIdx.x;   // 262144
    int lane = gid & 63;
    int fid = (gid >> 6) & 15;
    int kt = (gid >> 10) & 31;
    int bk = gid >> 15;
    int b = bk >> 2, kvh = bk & 3;
    int n = fid >> 2, c = fid & 3;
    int l16 = lane & 15, quad = lane >> 4;
    int s = kt * 64 + n * 16 + l16;
    const u16* src = QKV + (size_t)(b * 2048 + s) * 3072 + 2048 + kvh * 128 + c * 32 + quad * 8;
    *(short8*)&Kp[(size_t)gid * 8] = *(const short8*)src;
}

// ---------------- pack V into MFMA B-fragment order ----------------
// Vp[bk][kt][fid=nt*2+kc][lane][8] = V[b, s=kt*64+kc*32+quad*8+j, kvh, hd=nt*16+l16]
__global__ __launch_bounds__(256) void pack_v(const u16* __restrict__ QKV, u16* __restrict__ Vp) {
    int gid = blockIdx.x * 256 + threadIdx.x;
    int lane = gid & 63;
    int fid = (gid >> 6) & 15;
    int kt = (gid >> 10) & 31;
    int bk = gid >> 15;
    int b = bk >> 2, kvh = bk & 3;
    int nt = fid >> 1, kc = fid & 1;
    int l16 = lane & 15, quad = lane >> 4;
    int hd = nt * 16 + l16;
    int s0 = kt * 64 + kc * 32 + quad * 8;
    const u16* src = QKV + (size_t)(b * 2048 + s0) * 3072 + 2560 + kvh * 128 + hd;
    short8 v;
    #pragma unroll
    for (int j = 0; j < 8; j++) v[j] = (short)src[(size_t)j * 3072];
    *(short8*)&Vp[(size_t)gid * 8] = v;
}

// ---------------- Flash attention ----------------
// block = (bk, qt): 4 waves = 4 GQA heads of one kv-head, one 16-row q-tile.
// LDS exactly 40KB -> 4 blocks/CU = 16 waves/CU. Grid qt-descending (longest first).
__global__ __launch_bounds__(256, 4) void attn_kernel(const u16* __restrict__ QKV,
                                                      const u16* __restrict__ Kp,
                                                      const u16* __restrict__ Vp,
                                                      u16* __restrict__ Ob) {
    __shared__ u16 Ks[16 * 512];   // 16KB packed K tile
    __shared__ u16 Vs[16 * 512];   // 16KB packed V tile
    __shared__ u16 Ps[4 * 2048];   // 8KB: per-wave P region, XOR-swizzled (no padding)
    int bid = blockIdx.x;
    int bk = bid & 7;
    int qt = 127 - (bid >> 3);
    int b = bk >> 2, kvh = bk & 3;
    int t = threadIdx.x, lane = t & 63, w = t >> 6, quad = lane >> 4, l16 = lane & 15;
    int l7 = l16 & 7, hi = l16 >> 3;
    int h = kvh * 4 + w;
    const float kscale = 0.08838834764831845f * 1.4426950408889634f; // 1/sqrt(128)*log2e

    // Q fragments (A-layout): m = l16, k = c*32 + quad*8
    short8 qf[4];
    {
        const u16* qp = QKV + ((size_t)(b * S_ + qt * 16 + l16)) * 3072 + h * HD_ + quad * 8;
        #pragma unroll
        for (int c = 0; c < 4; c++) qf[c] = *(const short8*)(qp + c * 32);
    }
    // ones B-fragment for MFMA row-sum (l accumulator)
    short8 ones;
    #pragma unroll
    for (int j = 0; j < 8; j++) ones[j] = (short)0x3F80;

    float m_i[4];
    f4 ls = (f4){0.f, 0.f, 0.f, 0.f};
    f4 o[8];
    #pragma unroll
    for (int r = 0; r < 4; r++) m_i[r] = -1e30f;
    #pragma unroll
    for (int n = 0; n < 8; n++) o[n] = (f4){0.f, 0.f, 0.f, 0.f};

    const u16* Kpb = Kp + (size_t)bk * 32 * 8192;
    const u16* Vpb = Vp + (size_t)bk * 32 * 8192;
    u16* P = Ps + w * 2048;
    int nkt = (qt >> 2) + 1;

    for (int kt = 0; kt < nkt; kt++) {
        // stage packed K,V tiles: wave w stages fragments w*4..w*4+3 of each
        {
            const u16* ks = Kpb + (size_t)kt * 8192 + (w * 4) * 512 + lane * 8;
            const u16* vs = Vpb + (size_t)kt * 8192 + (w * 4) * 512 + lane * 8;
            #pragma unroll
            for (int i = 0; i < 4; i++) {
                GLDS16(ks + i * 512, &Ks[(w * 4 + i) * 512]);
                GLDS16(vs + i * 512, &Vs[(w * 4 + i) * 512]);
            }
        }
        __syncthreads();

        // QK^T (raw domain)
        f4 sc[4];
        #pragma unroll
        for (int n = 0; n < 4; n++) sc[n] = (f4){0.f, 0.f, 0.f, 0.f};
        #pragma unroll
        for (int n = 0; n < 4; n++) {
            #pragma unroll
            for (int c = 0; c < 4; c++) {
                short8 kf = *(const short8*)&Ks[(n * 4 + c) * 512 + lane * 8];
                sc[n] = __builtin_amdgcn_mfma_f32_16x16x32_bf16(qf[c], kf, sc[n], 0, 0, 0);
            }
        }
        // causal mask only on the diagonal k-tile (raw domain)
        if (kt == nkt - 1) {
            int qrow0 = qt * 16 + quad * 4;
            #pragma unroll
            for (int n = 0; n < 4; n++) {
                int colg = kt * 64 + n * 16 + l16;
                #pragma unroll
                for (int r = 0; r < 4; r++)
                    sc[n][r] = (colg <= qrow0 + r) ? sc[n][r] : -1e30f;
            }
        }
        // row max (raw domain): local over n, then 16-lane butterfly
        float mnew[4];
        bool chg = false;
        #pragma unroll
        for (int r = 0; r < 4; r++) {
            float mx = fmaxf(fmaxf(sc[0][r], sc[1][r]), fmaxf(sc[2][r], sc[3][r]));
            #pragma unroll
            for (int off = 1; off < 16; off <<= 1) mx = fmaxf(mx, __shfl_xor(mx, off, 64));
            mnew[r] = fmaxf(m_i[r], mx);
            chg |= (mnew[r] > m_i[r]);
        }
        if (__ballot(chg)) {
            #pragma unroll
            for (int r = 0; r < 4; r++) {
                float al = exp2f((m_i[r] - mnew[r]) * kscale);
                m_i[r] = mnew[r];
                ls[r] *= al;
                #pragma unroll
                for (int nt = 0; nt < 8; nt++) o[nt][r] *= al;
            }
        }
        // P = exp2(s*kscale - m*kscale), truncate-pack to bf16, swizzled LDS write
        float mk[4];
        #pragma unroll
        for (int r = 0; r < 4; r++) mk[r] = m_i[r] * kscale;
        #pragma unroll
        for (int n = 0; n < 4; n++) {
            #pragma unroll
            for (int r = 0; r < 4; r++) {
                float p = exp2f(__builtin_fmaf(sc[n][r], kscale, -mk[r]));
                union { float f; unsigned int u; } cv; cv.f = p;
                int row = quad * 4 + r;
                int sw = (n * 2 + hi) ^ (row & 7);
                P[row * 64 + sw * 8 + l7] = (u16)(cv.u >> 16);
            }
        }
        __asm__ volatile("s_waitcnt lgkmcnt(0)" ::: "memory");

        // PV: O += P @ V ; l += P @ ones (MFMA row-sum)
        #pragma unroll
        for (int kc = 0; kc < 2; kc++) {
            short8 af = *(const short8*)&P[l16 * 64 + (((kc * 4 + quad) ^ l7) << 3)];
            ls = __builtin_amdgcn_mfma_f32_16x16x32_bf16(af, ones, ls, 0, 0, 0);
            #pragma unroll
            for (int nt = 0; nt < 8; nt++) {
                short8 vf = *(const short8*)&Vs[(nt * 2 + kc) * 512 + lane * 8];
                o[nt] = __builtin_amdgcn_mfma_f32_16x16x32_bf16(af, vf, o[nt], 0, 0, 0);
            }
        }
        __syncthreads();
    }
    // epilogue: every lane already holds full row sums in ls
    float rl[4];
    #pragma unroll
    for (int r = 0; r < 4; r++) rl[r] = 1.0f / ls[r];
    #pragma unroll
    for (int nt = 0; nt < 8; nt++)
        #pragma unroll
        for (int r = 0; r < 4; r++) {
            size_t row = (size_t)b * S_ + qt * 16 + quad * 4 + r;
            Ob[row * 2048 + h * HD_ + nt * 16 + l16] = f2bf(o[nt][r] * rl[r]);
        }
}

extern "C" void kernel_launch(void* const* d_in, const int* in_sizes, int n_in,
                              void* d_out, int out_size, void* d_ws, size_t ws_size,
                              hipStream_t stream) {
    const float* x     = (const float*)d_in[0];
    const float* freqs = (const float*)d_in[1];
    const float* wq    = (const float*)d_in[2];
    const float* wk    = (const float*)d_in[3];
    const float* wv    = (const float*)d_in[4];
    const float* wo    = (const float*)d_in[5];
    float* out = (float*)d_out;

    char* p = (char*)d_ws;
    u16* xb    = (u16*)p; p += (size_t)4096 * 2048 * 2;   // 16MB
    u16* wqkvb = (u16*)p; p += (size_t)3072 * 2048 * 2;   // 12MB
    u16* wob   = (u16*)p; p += (size_t)2048 * 2048 * 2;   // 8MB
    u16* QKVb  = (u16*)p; p += (size_t)4096 * 3072 * 2;   // 24MB
    u16* Kpb   = (u16*)p; p += (size_t)8 * 32 * 8192 * 2; // 4MB
    u16* Vpb   = (u16*)p; p += (size_t)8 * 32 * 8192 * 2; // 4MB
    u16* attnb = xb;  // reuse

    cast4_kernel<<<8192, 256, 0, stream>>>(x, xb, 2097152);
    cast4_kernel<<<4096, 256, 0, stream>>>(wq, wqkvb, 1048576);
    cast4_kernel<<<1024, 256, 0, stream>>>(wk, wqkvb + (size_t)2048 * 2048, 262144);
    cast4_kernel<<<1024, 256, 0, stream>>>(wv, wqkvb + (size_t)2560 * 2048, 262144);
    cast4_kernel<<<4096, 256, 0, stream>>>(wo, wob, 1048576);

    gemm_bt<true><<<dim3(24, 32), 256, 0, stream>>>(xb, wqkvb, QKVb, 4096, 3072, 2048);

    rope_kernel<<<dim3(5, 4096), 256, 0, stream>>>(QKVb, freqs);

    pack_k<<<1024, 256, 0, stream>>>(QKVb, Kpb);
    pack_v<<<1024, 256, 0, stream>>>(QKVb, Vpb);

    attn_kernel<<<1024, 256, 0, stream>>>(QKVb, Kpb, Vpb, attnb);

    gemm_bt<false><<<dim3(16, 32), 256, 0, stream>>>(attnb, wob, out, 4096, 2048, 2048);
}